// Round 3
// baseline (275.458 us; speedup 1.0000x reference)
//
#include <hip/hip_runtime.h>
#include <hip/hip_bf16.h>

#define BB 4096
#define TT 200
#define LL 8
#define VV 64
#define CC 16
#define NBERN 32
#define CLIP 20.0f
#define TC 20                      // t-chunk per wave in link kernel
#define NCH (TT / TC)              // 10 chunks per b

// ---------------- Phase A: z recurrence, 8 lanes per b ----------------
// lane j = threadIdx & 7 owns state component j; group of 8 lanes = one b.
// Cross-component matvec via intra-group shuffles (ds_bpermute).
__global__ __launch_bounds__(256) void var1_fast(
    const float* __restrict__ eps,        // (B,T,L)
    const float* __restrict__ A,          // (L,L)
    const float* __restrict__ logvar_z1,  // (L)
    const float* __restrict__ beta0,      // (L)
    const float* __restrict__ beta1,      // (L)
    float* __restrict__ zout)             // (B,T,L) in ws
{
    const int tid  = blockIdx.x * 256 + threadIdx.x;
    const int b    = tid >> 3;            // 8 lanes per b
    const int j    = tid & 7;             // state component
    const int lane = threadIdx.x & 63;
    const int gbase = lane & 56;          // first lane of my 8-lane group

    // per-lane: column j of A, betas, init scale
    float Acol[LL];
#pragma unroll
    for (int l = 0; l < LL; ++l) Acol[l] = A[l * LL + j];
    const float bb0 = beta0[j];
    const float bb1 = beta1[j];
    const float s1  = __expf(0.5f * logvar_z1[j]);

    const float* ep = eps + (size_t)b * TT * LL + j;
    float* zb = zout + (size_t)b * TT * LL + j;

    // t = 0
    float zj = ep[0] * s1;
    zb[0] = zj;

    // 4-deep eps prefetch ring
    float ebuf[4];
#pragma unroll
    for (int k = 0; k < 4; ++k) ebuf[k] = ep[(size_t)(1 + k) * LL];

#pragma unroll 4
    for (int t = 1; t < TT; ++t) {
        const int slot = (t - 1) & 3;
        const float cur = ebuf[slot];
        const int tn = t + 4;
        if (tn < TT) ebuf[slot] = ep[(size_t)tn * LL];

        // gather group's z components and do the matvec
        float a = fmaf(bb1, (float)t, bb0) + cur;
#pragma unroll
        for (int l = 0; l < LL; ++l) {
            const float zl = __shfl(zj, gbase + l);
            a = fmaf(zl, Acol[l], a);
        }
        zj = a;
        zb[(size_t)t * LL] = zj;
    }
}

// ---------------- Phase B: link map, one wave per (b, t-chunk) ----------------
// lane = v. x/z rows are wave-uniform -> direct global loads (1 txn each), no LDS.
__global__ __launch_bounds__(256) void link_kernel(
    const float* __restrict__ z,          // (B,T,L) from ws
    const float* __restrict__ u,          // (B,1,V)
    const float* __restrict__ x,          // (B,T,C)
    const float* __restrict__ intercepts, // (V)
    const float* __restrict__ wz,         // (L,V)
    const float* __restrict__ wx,         // (C,V)
    const float* __restrict__ logvar_u,   // (V)
    float* __restrict__ linpar_out,       // (B,T,V)
    float* __restrict__ condmean_out)     // (B,T,V)
{
    const int w    = threadIdx.x >> 6;
    const int lane = threadIdx.x & 63;
    const int gw   = blockIdx.x * 4 + w;       // global wave id
    const int b    = gw / NCH;
    const int t0   = (gw - b * NCH) * TC;
    const int v    = lane;

    // per-lane weights
    float wxv[CC];
#pragma unroll
    for (int c = 0; c < CC; ++c) wxv[c] = wx[c * VV + v];
    float wzv[LL];
#pragma unroll
    for (int l = 0; l < LL; ++l) wzv[l] = wz[l * VV + v];
    const float base = intercepts[v] + u[(size_t)b * VV + v] * __expf(0.5f * logvar_u[v]);

    const float4* gx = (const float4*)(x + ((size_t)b * TT + t0) * CC);  // 4 float4 per t
    const float4* gz = (const float4*)(z + ((size_t)b * TT + t0) * LL);  // 2 float4 per t

    float* lp = linpar_out   + ((size_t)b * TT + t0) * VV + v;
    float* cm = condmean_out + ((size_t)b * TT + t0) * VV + v;

    // 1-deep prefetch of next t's rows
    float4 x0 = gx[0], x1 = gx[1], x2 = gx[2], x3 = gx[3];
    float4 z0 = gz[0], z1 = gz[1];

    for (int tt = 0; tt < TC; ++tt) {
        const float4 cx0 = x0, cx1 = x1, cx2 = x2, cx3 = x3;
        const float4 cz0 = z0, cz1 = z1;
        if (tt + 1 < TC) {
            x0 = gx[(tt + 1) * 4 + 0]; x1 = gx[(tt + 1) * 4 + 1];
            x2 = gx[(tt + 1) * 4 + 2]; x3 = gx[(tt + 1) * 4 + 3];
            z0 = gz[(tt + 1) * 2 + 0]; z1 = gz[(tt + 1) * 2 + 1];
        }

        float acc = base;
        acc = fmaf(cx0.x, wxv[0],  acc); acc = fmaf(cx0.y, wxv[1],  acc);
        acc = fmaf(cx0.z, wxv[2],  acc); acc = fmaf(cx0.w, wxv[3],  acc);
        acc = fmaf(cx1.x, wxv[4],  acc); acc = fmaf(cx1.y, wxv[5],  acc);
        acc = fmaf(cx1.z, wxv[6],  acc); acc = fmaf(cx1.w, wxv[7],  acc);
        acc = fmaf(cx2.x, wxv[8],  acc); acc = fmaf(cx2.y, wxv[9],  acc);
        acc = fmaf(cx2.z, wxv[10], acc); acc = fmaf(cx2.w, wxv[11], acc);
        acc = fmaf(cx3.x, wxv[12], acc); acc = fmaf(cx3.y, wxv[13], acc);
        acc = fmaf(cx3.z, wxv[14], acc); acc = fmaf(cx3.w, wxv[15], acc);
        acc = fmaf(cz0.x, wzv[0],  acc); acc = fmaf(cz0.y, wzv[1],  acc);
        acc = fmaf(cz0.z, wzv[2],  acc); acc = fmaf(cz0.w, wzv[3],  acc);
        acc = fmaf(cz1.x, wzv[4],  acc); acc = fmaf(cz1.y, wzv[5],  acc);
        acc = fmaf(cz1.z, wzv[6],  acc); acc = fmaf(cz1.w, wzv[7],  acc);

        acc = fminf(fmaxf(acc, -CLIP), CLIP);
        float cmv = (v < NBERN) ? (1.0f / (1.0f + __expf(-acc))) : __expf(acc);
        lp[(size_t)tt * VV] = acc;
        cm[(size_t)tt * VV] = cmv;
    }
}

// ---------------- fallback: fused kernel (if ws too small) ----------------
__global__ __launch_bounds__(256) void vargllvm_fused(
    const float* __restrict__ eps, const float* __restrict__ u,
    const float* __restrict__ x, const float* __restrict__ A,
    const float* __restrict__ logvar_z1, const float* __restrict__ beta0,
    const float* __restrict__ beta1, const float* __restrict__ intercepts,
    const float* __restrict__ wz, const float* __restrict__ wx,
    const float* __restrict__ logvar_u,
    float* __restrict__ linpar_out, float* __restrict__ condmean_out)
{
    const int wave = threadIdx.x >> 6;
    const int lane = threadIdx.x & 63;
    const int b    = blockIdx.x * 4 + wave;
    const int v    = lane;

    float wxv[CC];
#pragma unroll
    for (int c = 0; c < CC; ++c) wxv[c] = wx[c * VV + v];
    float wzv[LL];
#pragma unroll
    for (int l = 0; l < LL; ++l) wzv[l] = wz[l * VV + v];
    const float base = intercepts[v] + u[(size_t)b * VV + v] * __expf(0.5f * logvar_u[v]);

    float Ar[LL][LL];
#pragma unroll
    for (int l = 0; l < LL; ++l)
#pragma unroll
        for (int j = 0; j < LL; ++j) Ar[l][j] = A[l * LL + j];
    float b0[LL], b1[LL];
#pragma unroll
    for (int j = 0; j < LL; ++j) { b0[j] = beta0[j]; b1[j] = beta1[j]; }

    const float* epsb = eps + (size_t)b * TT * LL;
    const float* xb   = x   + (size_t)b * TT * CC;
    float* lp = linpar_out   + (size_t)b * TT * VV + v;
    float* cm = condmean_out + (size_t)b * TT * VV + v;

    float z[LL];
#pragma unroll
    for (int j = 0; j < LL; ++j) z[j] = epsb[j] * __expf(0.5f * logvar_z1[j]);

    for (int t = 0; t < TT; ++t) {
        if (t > 0) {
            float zn[LL];
            const float tf = (float)t;
#pragma unroll
            for (int j = 0; j < LL; ++j) {
                float a = fmaf(b1[j], tf, b0[j]) + epsb[t * LL + j];
#pragma unroll
                for (int l = 0; l < LL; ++l) a = fmaf(z[l], Ar[l][j], a);
                zn[j] = a;
            }
#pragma unroll
            for (int j = 0; j < LL; ++j) z[j] = zn[j];
        }
        float acc = base;
#pragma unroll
        for (int c = 0; c < CC; ++c) acc = fmaf(xb[t * CC + c], wxv[c], acc);
#pragma unroll
        for (int l = 0; l < LL; ++l) acc = fmaf(z[l], wzv[l], acc);
        acc = fminf(fmaxf(acc, -CLIP), CLIP);
        float cmv = (v < NBERN) ? (1.0f / (1.0f + __expf(-acc))) : __expf(acc);
        lp[(size_t)t * VV] = acc;
        cm[(size_t)t * VV] = cmv;
    }
}

extern "C" void kernel_launch(void* const* d_in, const int* in_sizes, int n_in,
                              void* d_out, int out_size, void* d_ws, size_t ws_size,
                              hipStream_t stream) {
    const float* eps        = (const float*)d_in[0];
    const float* u          = (const float*)d_in[1];
    const float* x          = (const float*)d_in[2];
    const float* A          = (const float*)d_in[3];
    const float* logvar_z1  = (const float*)d_in[4];
    const float* beta0      = (const float*)d_in[5];
    const float* beta1      = (const float*)d_in[6];
    const float* intercepts = (const float*)d_in[7];
    const float* wz         = (const float*)d_in[8];
    const float* wx         = (const float*)d_in[9];
    const float* logvar_u   = (const float*)d_in[10];

    float* linpar   = (float*)d_out;
    float* condmean = (float*)d_out + (size_t)BB * TT * VV;

    const size_t z_bytes = (size_t)BB * TT * LL * sizeof(float);
    if (ws_size >= z_bytes) {
        float* zws = (float*)d_ws;
        hipLaunchKernelGGL(var1_fast, dim3(BB * LL / 256), dim3(256), 0, stream,
                           eps, A, logvar_z1, beta0, beta1, zws);
        const int nwaves = BB * NCH;
        hipLaunchKernelGGL(link_kernel, dim3(nwaves / 4), dim3(256), 0, stream,
                           zws, u, x, intercepts, wz, wx, logvar_u, linpar, condmean);
    } else {
        hipLaunchKernelGGL(vargllvm_fused, dim3(BB / 4), dim3(256), 0, stream,
                           eps, u, x, A, logvar_z1, beta0, beta1,
                           intercepts, wz, wx, logvar_u, linpar, condmean);
    }
}

// Round 4
// 144.974 us; speedup vs baseline: 1.9001x; 1.9001x over previous
//
#include <hip/hip_runtime.h>
#include <hip/hip_bf16.h>

#define BB 4096
#define TT 200
#define LL 8
#define VV 64
#define CC 16
#define NBERN 32
#define CLIP 20.0f
#define TC 20                      // t-chunk per wave in link kernel
#define NCH (TT / TC)              // 10 chunks per b

// ---------------- Phase A: z recurrence, 8 lanes per b ----------------
// lane j = tid & 7 owns state component j; group of 8 lanes = one b.
__global__ __launch_bounds__(256) void var1_fast(
    const float* __restrict__ eps,        // (B,T,L)
    const float* __restrict__ A,          // (L,L)
    const float* __restrict__ logvar_z1,  // (L)
    const float* __restrict__ beta0,      // (L)
    const float* __restrict__ beta1,      // (L)
    float* __restrict__ zout)             // (B,T,L) in ws
{
    const int tid  = blockIdx.x * 256 + threadIdx.x;
    const int b    = tid >> 3;            // 8 lanes per b
    const int j    = tid & 7;             // state component
    const int lane = threadIdx.x & 63;
    const int gbase = lane & 56;          // first lane of my 8-lane group

    float Acol[LL];
#pragma unroll
    for (int l = 0; l < LL; ++l) Acol[l] = A[l * LL + j];
    const float bb0 = beta0[j];
    const float bb1 = beta1[j];
    const float s1  = __expf(0.5f * logvar_z1[j]);

    const float* ep = eps + (size_t)b * TT * LL + j;
    float* zb = zout + (size_t)b * TT * LL + j;

    float zj = ep[0] * s1;
    zb[0] = zj;

    float ebuf[4];
#pragma unroll
    for (int k = 0; k < 4; ++k) ebuf[k] = ep[(size_t)(1 + k) * LL];

#pragma unroll 4
    for (int t = 1; t < TT; ++t) {
        const int slot = (t - 1) & 3;
        const float cur = ebuf[slot];
        const int tn = t + 4;
        if (tn < TT) ebuf[slot] = ep[(size_t)tn * LL];

        float a = fmaf(bb1, (float)t, bb0) + cur;
#pragma unroll
        for (int l = 0; l < LL; ++l) {
            const float zl = __shfl(zj, gbase + l);
            a = fmaf(zl, Acol[l], a);
        }
        zj = a;
        zb[(size_t)t * LL] = zj;
    }
}

// ---------------- Phase B: link map, one wave per (b, t-chunk) ----------------
// lane = v. x/z staged in wave-private LDS (coalesced float4 loads, broadcast
// ds_read_b128 consumption). 4 partial accumulators break the FMA chain.
__global__ __launch_bounds__(256) void link_kernel(
    const float* __restrict__ z,          // (B,T,L) from ws
    const float* __restrict__ u,          // (B,1,V)
    const float* __restrict__ x,          // (B,T,C)
    const float* __restrict__ intercepts, // (V)
    const float* __restrict__ wz,         // (L,V)
    const float* __restrict__ wx,         // (C,V)
    const float* __restrict__ logvar_u,   // (V)
    float* __restrict__ linpar_out,       // (B,T,V)
    float* __restrict__ condmean_out)     // (B,T,V)
{
    const int w    = threadIdx.x >> 6;
    const int lane = threadIdx.x & 63;
    const int gw   = blockIdx.x * 4 + w;       // global wave id
    const int b    = gw / NCH;
    const int t0   = (gw - b * NCH) * TC;
    const int v    = lane;

    __shared__ __align__(16) float xs[4][TC * CC];  // 4 x 320 floats
    __shared__ __align__(16) float zs[4][TC * LL];  // 4 x 160 floats

    float wxv[CC];
#pragma unroll
    for (int c = 0; c < CC; ++c) wxv[c] = wx[c * VV + v];
    float wzv[LL];
#pragma unroll
    for (int l = 0; l < LL; ++l) wzv[l] = wz[l * VV + v];
    const float base = intercepts[v] + u[(size_t)b * VV + v] * __expf(0.5f * logvar_u[v]);

    // stage chunk, vectorized (wave-private: no barrier needed)
    const float4* gx4 = (const float4*)(x + ((size_t)b * TT + t0) * CC);  // 80 vec4
    const float4* gz4 = (const float4*)(z + ((size_t)b * TT + t0) * LL);  // 40 vec4
    float4* xs4 = (float4*)xs[w];
    float4* zs4 = (float4*)zs[w];
#pragma unroll
    for (int i = lane; i < TC * CC / 4; i += 64) xs4[i] = gx4[i];   // 2 iters
    if (lane < TC * LL / 4) zs4[lane] = gz4[lane];                   // 40 lanes

    float* lp = linpar_out   + ((size_t)b * TT + t0) * VV + v;
    float* cm = condmean_out + ((size_t)b * TT + t0) * VV + v;

#pragma unroll 2
    for (int tt = 0; tt < TC; ++tt) {
        const float4* xr = (const float4*)&xs[w][tt * CC];
        const float4* zr = (const float4*)&zs[w][tt * LL];
        const float4 x0 = xr[0], x1 = xr[1], x2 = xr[2], x3 = xr[3];
        const float4 z0 = zr[0], z1 = zr[1];

        float a0 = base, a1 = 0.f, a2 = 0.f, a3 = 0.f;
        a0 = fmaf(x0.x, wxv[0],  a0); a0 = fmaf(x0.y, wxv[1],  a0);
        a0 = fmaf(x0.z, wxv[2],  a0); a0 = fmaf(x0.w, wxv[3],  a0);
        a1 = fmaf(x1.x, wxv[4],  a1); a1 = fmaf(x1.y, wxv[5],  a1);
        a1 = fmaf(x1.z, wxv[6],  a1); a1 = fmaf(x1.w, wxv[7],  a1);
        a2 = fmaf(x2.x, wxv[8],  a2); a2 = fmaf(x2.y, wxv[9],  a2);
        a2 = fmaf(x2.z, wxv[10], a2); a2 = fmaf(x2.w, wxv[11], a2);
        a3 = fmaf(x3.x, wxv[12], a3); a3 = fmaf(x3.y, wxv[13], a3);
        a3 = fmaf(x3.z, wxv[14], a3); a3 = fmaf(x3.w, wxv[15], a3);
        a0 = fmaf(z0.x, wzv[0],  a0); a0 = fmaf(z0.y, wzv[1],  a0);
        a1 = fmaf(z0.z, wzv[2],  a1); a1 = fmaf(z0.w, wzv[3],  a1);
        a2 = fmaf(z1.x, wzv[4],  a2); a2 = fmaf(z1.y, wzv[5],  a2);
        a3 = fmaf(z1.z, wzv[6],  a3); a3 = fmaf(z1.w, wzv[7],  a3);

        float acc = (a0 + a1) + (a2 + a3);
        acc = fminf(fmaxf(acc, -CLIP), CLIP);
        float cmv = (v < NBERN) ? (1.0f / (1.0f + __expf(-acc))) : __expf(acc);
        lp[(size_t)tt * VV] = acc;
        cm[(size_t)tt * VV] = cmv;
    }
}

// ---------------- fallback: fused kernel (if ws too small) ----------------
__global__ __launch_bounds__(256) void vargllvm_fused(
    const float* __restrict__ eps, const float* __restrict__ u,
    const float* __restrict__ x, const float* __restrict__ A,
    const float* __restrict__ logvar_z1, const float* __restrict__ beta0,
    const float* __restrict__ beta1, const float* __restrict__ intercepts,
    const float* __restrict__ wz, const float* __restrict__ wx,
    const float* __restrict__ logvar_u,
    float* __restrict__ linpar_out, float* __restrict__ condmean_out)
{
    const int wave = threadIdx.x >> 6;
    const int lane = threadIdx.x & 63;
    const int b    = blockIdx.x * 4 + wave;
    const int v    = lane;

    float wxv[CC];
#pragma unroll
    for (int c = 0; c < CC; ++c) wxv[c] = wx[c * VV + v];
    float wzv[LL];
#pragma unroll
    for (int l = 0; l < LL; ++l) wzv[l] = wz[l * VV + v];
    const float base = intercepts[v] + u[(size_t)b * VV + v] * __expf(0.5f * logvar_u[v]);

    float Ar[LL][LL];
#pragma unroll
    for (int l = 0; l < LL; ++l)
#pragma unroll
        for (int j = 0; j < LL; ++j) Ar[l][j] = A[l * LL + j];
    float b0[LL], b1[LL];
#pragma unroll
    for (int j = 0; j < LL; ++j) { b0[j] = beta0[j]; b1[j] = beta1[j]; }

    const float* epsb = eps + (size_t)b * TT * LL;
    const float* xb   = x   + (size_t)b * TT * CC;
    float* lp = linpar_out   + (size_t)b * TT * VV + v;
    float* cm = condmean_out + (size_t)b * TT * VV + v;

    float z[LL];
#pragma unroll
    for (int j = 0; j < LL; ++j) z[j] = epsb[j] * __expf(0.5f * logvar_z1[j]);

    for (int t = 0; t < TT; ++t) {
        if (t > 0) {
            float zn[LL];
            const float tf = (float)t;
#pragma unroll
            for (int j = 0; j < LL; ++j) {
                float a = fmaf(b1[j], tf, b0[j]) + epsb[t * LL + j];
#pragma unroll
                for (int l = 0; l < LL; ++l) a = fmaf(z[l], Ar[l][j], a);
                zn[j] = a;
            }
#pragma unroll
            for (int j = 0; j < LL; ++j) z[j] = zn[j];
        }
        float acc = base;
#pragma unroll
        for (int c = 0; c < CC; ++c) acc = fmaf(xb[t * CC + c], wxv[c], acc);
#pragma unroll
        for (int l = 0; l < LL; ++l) acc = fmaf(z[l], wzv[l], acc);
        acc = fminf(fmaxf(acc, -CLIP), CLIP);
        float cmv = (v < NBERN) ? (1.0f / (1.0f + __expf(-acc))) : __expf(acc);
        lp[(size_t)t * VV] = acc;
        cm[(size_t)t * VV] = cmv;
    }
}

extern "C" void kernel_launch(void* const* d_in, const int* in_sizes, int n_in,
                              void* d_out, int out_size, void* d_ws, size_t ws_size,
                              hipStream_t stream) {
    const float* eps        = (const float*)d_in[0];
    const float* u          = (const float*)d_in[1];
    const float* x          = (const float*)d_in[2];
    const float* A          = (const float*)d_in[3];
    const float* logvar_z1  = (const float*)d_in[4];
    const float* beta0      = (const float*)d_in[5];
    const float* beta1      = (const float*)d_in[6];
    const float* intercepts = (const float*)d_in[7];
    const float* wz         = (const float*)d_in[8];
    const float* wx         = (const float*)d_in[9];
    const float* logvar_u   = (const float*)d_in[10];

    float* linpar   = (float*)d_out;
    float* condmean = (float*)d_out + (size_t)BB * TT * VV;

    const size_t z_bytes = (size_t)BB * TT * LL * sizeof(float);
    if (ws_size >= z_bytes) {
        float* zws = (float*)d_ws;
        hipLaunchKernelGGL(var1_fast, dim3(BB * LL / 256), dim3(256), 0, stream,
                           eps, A, logvar_z1, beta0, beta1, zws);
        const int nwaves = BB * NCH;
        hipLaunchKernelGGL(link_kernel, dim3(nwaves / 4), dim3(256), 0, stream,
                           zws, u, x, intercepts, wz, wx, logvar_u, linpar, condmean);
    } else {
        hipLaunchKernelGGL(vargllvm_fused, dim3(BB / 4), dim3(256), 0, stream,
                           eps, u, x, A, logvar_z1, beta0, beta1,
                           intercepts, wz, wx, logvar_u, linpar, condmean);
    }
}